// Round 10
// baseline (309.479 us; speedup 1.0000x reference)
//
#include <hip/hip_runtime.h>
#include <math.h>
#include <stdint.h>

#define B_ 4
#define T_ 2048
#define C_ 1024
#define H_ 16
#define G_ 4
#define D_ 64
#define KVC_ 512    // 2*G*D
#define QKV_ 1536   // C + 2*G*D  (packed QKV row stride)
#define KOFF_ 1024  // K block col offset in packed row
#define VOFF_ 1280  // V block col offset in packed row

typedef unsigned short u16;
typedef short bf16x8 __attribute__((ext_vector_type(8)));
typedef float f32x4 __attribute__((ext_vector_type(4)));

__device__ __forceinline__ u16 f2bf(float f) {
  uint32_t u = __builtin_bit_cast(uint32_t, f);
  u += 0x7fffu + ((u >> 16) & 1u);   // RNE
  return (u16)(u >> 16);
}

__device__ __forceinline__ void gload16(const void* g, void* l) {
  __builtin_amdgcn_global_load_lds((const __attribute__((address_space(1))) void*)g,
                                   (__attribute__((address_space(3))) void*)l, 16, 0, 0);
}

// ---------------------------------------------------------------------------
// fp32 -> bf16 (scale folded in), vectorized x4
// ---------------------------------------------------------------------------
__global__ __launch_bounds__(256)
void cvt_bf16(const float* __restrict__ s, u16* __restrict__ d, int n4, float scale) {
  int i = blockIdx.x * 256 + threadIdx.x;
  const int stride = gridDim.x * 256;
  for (; i < n4; i += stride) {
    const float4 v = ((const float4*)s)[i];
    uint2 o;
    o.x = (uint32_t)f2bf(v.x * scale) | ((uint32_t)f2bf(v.y * scale) << 16);
    o.y = (uint32_t)f2bf(v.z * scale) | ((uint32_t)f2bf(v.w * scale) << 16);
    ((uint2*)d)[i] = o;
  }
}

// ---------------------------------------------------------------------------
// bf16 GEMM, m97 structure: out[M,N] = A[M,K] @ W[N,K]^T  (unchanged, measured)
// ---------------------------------------------------------------------------
template <int OUTF32>
__global__ __launch_bounds__(256)
void gemm_bf16(const u16* __restrict__ A, const u16* __restrict__ W,
               const float* __restrict__ bias, void* __restrict__ outp,
               int N, int K) {
  __shared__ __align__(16) u16 As[128 * 32];
  __shared__ __align__(16) u16 Ws[128 * 32];
  const int tid = threadIdx.x;
  const int l = tid & 63, w = tid >> 6;
  const int lhi = l >> 4, llo = l & 15;
  const int wr = w >> 1, wc = w & 1;
  const int m0 = blockIdx.x * 128, n0 = blockIdx.y * 128;

  const u16* a_src = A + (size_t)(m0 + 32 * w + (l >> 2)) * K + 8 * (l & 3);
  const u16* w_src = W + (size_t)(n0 + 32 * w + (l >> 2)) * K + 8 * (l & 3);
  u16* asl = As + 1024 * w;
  u16* wsl = Ws + 1024 * w;

  const f32x4 zero4 = {0.f, 0.f, 0.f, 0.f};
  f32x4 acc[4][4];
#pragma unroll
  for (int i = 0; i < 4; ++i)
#pragma unroll
    for (int j = 0; j < 4; ++j) acc[i][j] = zero4;

  for (int k0 = 0; k0 < K; k0 += 32) {
    __syncthreads();
    gload16(a_src + k0, asl);
    gload16(a_src + k0 + 16 * K, asl + 512);
    gload16(w_src + k0, wsl);
    gload16(w_src + k0 + 16 * K, wsl + 512);
    __syncthreads();
    bf16x8 af[4], wf[4];
#pragma unroll
    for (int mt = 0; mt < 4; ++mt)
      af[mt] = *(const bf16x8*)(As + (wr * 64 + mt * 16 + llo) * 32 + lhi * 8);
#pragma unroll
    for (int nt = 0; nt < 4; ++nt)
      wf[nt] = *(const bf16x8*)(Ws + (wc * 64 + nt * 16 + llo) * 32 + lhi * 8);
#pragma unroll
    for (int mt = 0; mt < 4; ++mt)
#pragma unroll
      for (int nt = 0; nt < 4; ++nt)
        acc[mt][nt] = __builtin_amdgcn_mfma_f32_16x16x32_bf16(af[mt], wf[nt], acc[mt][nt], 0, 0, 0);
  }

#pragma unroll
  for (int mt = 0; mt < 4; ++mt)
#pragma unroll
    for (int nt = 0; nt < 4; ++nt)
#pragma unroll
      for (int r = 0; r < 4; ++r) {
        const int row = m0 + wr * 64 + mt * 16 + 4 * lhi + r;
        const int col = n0 + wc * 64 + nt * 16 + llo;
        if (OUTF32)
          ((float*)outp)[(size_t)row * N + col] = acc[mt][nt][r] + bias[col];
        else
          ((u16*)outp)[(size_t)row * N + col] = f2bf(acc[mt][nt][r]);
      }
}

// ---------------------------------------------------------------------------
// MFMA flash attention v3. v2 structure + softmax VALU/chain trim:
// exp2-domain scores (log2e folded into Wq), defer-rescale THR=8, deferred
// l-reduction, tree max/sum, cvt_pk P-pack, setprio around MFMA clusters.
// ---------------------------------------------------------------------------
__global__ __launch_bounds__(512)
void attn_kernel(const u16* __restrict__ QKVb, u16* __restrict__ Yb) {
  const int qtb = 15 - blockIdx.x;    // longest-first
  const int bh = blockIdx.y;
  const int b = bh >> 4, h = bh & 15, g = h & (G_ - 1);
  const int tid = threadIdx.x;
  const int l = tid & 63, w = tid >> 6;          // 8 waves
  const int lhi = l >> 4, llo = l & 15, l7 = l & 7;

  __shared__ __align__(16) u16 Ks[2][64 * 64];   // [kr][d], chunk ^ (kr&7)
  __shared__ __align__(16) u16 Vt[2][64 * 64];   // [d][kr], chunk ^ (d&7) ^ ((d>>3)&7)
  __shared__ __align__(16) u16 Ps[8][16 * 64];   // per-wave [q][kr], chunk ^ (q&7)

  const int q0 = qtb * 128;
  const int qrow = q0 + 16 * w + llo;            // this lane's q (as S^T col)
  const u16* qptr = QKVb + (size_t)(b * T_ + qrow) * QKV_ + h * D_ + 8 * lhi;
  const bf16x8 qf0 = *(const bf16x8*)(qptr);
  const bf16x8 qf1 = *(const bf16x8*)(qptr + 32);

  const f32x4 zero4 = {0.f, 0.f, 0.f, 0.f};
  f32x4 o[4];
#pragma unroll
  for (int i = 0; i < 4; ++i) o[i] = zero4;
  float m_s = -__builtin_inff();
  float l_p = 0.f;                               // per-lane partial (16 kr slice)

  // staging geometry
  const int skr = tid >> 3;                      // K: row 0..63
  const int ksrc_off = 8 * ((tid & 7) ^ (skr & 7));   // pre-swizzled source chunk
  const int vkr = 2 * (tid >> 4);                // V: row pair 0..62
  const int vd4 = 4 * (tid & 15);                // V: 4-d chunk
  u16* Pw = Ps[w];
  const int rbase = 4 * lhi;
  const int qmax_w = q0 + 16 * w + 15;           // wave's max q row
  const int ntiles = 2 * qtb + 2;

  // ---- prologue: stage tile 0 into buffer 0 ----
  {
    const int kv0 = b * T_;
    gload16(QKVb + (size_t)(kv0 + skr) * QKV_ + KOFF_ + g * D_ + ksrc_off,
            Ks[0] + 512 * w);
    const u16* vsrc = QKVb + (size_t)(kv0 + vkr) * QKV_ + VOFF_ + g * D_ + vd4;
    const uint2 a = *(const uint2*)vsrc;
    const uint2 c = *(const uint2*)(vsrc + QKV_);
    const u16* p0 = (const u16*)&a;
    const u16* p1 = (const u16*)&c;
#pragma unroll
    for (int i = 0; i < 4; ++i) {
      const int d = vd4 + i;
      const uint32_t val = (uint32_t)p0[i] | ((uint32_t)p1[i] << 16);
      const int p = (vkr >> 3) ^ (d & 7) ^ ((d >> 3) & 7);
      *(uint32_t*)((char*)Vt[0] + d * 128 + (p << 4) + (vkr & 7) * 2) = val;
    }
  }
  __syncthreads();

  int cur = 0;
  for (int kt = 0; kt < ntiles; ++kt) {
    const bool have_next = (kt + 1) < ntiles;
    uint2 vr0, vr1;
    // ---- issue next tile's loads (K direct to LDS, V to regs) ----
    if (have_next) {
      const int kv0n = b * T_ + (kt + 1) * 64;
      gload16(QKVb + (size_t)(kv0n + skr) * QKV_ + KOFF_ + g * D_ + ksrc_off,
              Ks[cur ^ 1] + 512 * w);
      const u16* vsrc = QKVb + (size_t)(kv0n + vkr) * QKV_ + VOFF_ + g * D_ + vd4;
      vr0 = *(const uint2*)vsrc;
      vr1 = *(const uint2*)(vsrc + QKV_);
    }

    // ---- compute on current buffers (skip fully-masked tiles for this wave) --
    if (kt * 64 <= qmax_w) {
      f32x4 st[4];
#pragma unroll
      for (int mt = 0; mt < 4; ++mt) st[mt] = zero4;
      __builtin_amdgcn_s_setprio(1);
#pragma unroll
      for (int mt = 0; mt < 4; ++mt) {
        const int krow = 16 * mt + llo;
        const u16* kb = Ks[cur] + krow * 64;
        const bf16x8 kf0 = *(const bf16x8*)(kb + ((lhi ^ l7) << 3));
        const bf16x8 kf1 = *(const bf16x8*)(kb + (((lhi + 4) ^ l7) << 3));
        st[mt] = __builtin_amdgcn_mfma_f32_16x16x32_bf16(kf0, qf0, st[mt], 0, 0, 0);
        st[mt] = __builtin_amdgcn_mfma_f32_16x16x32_bf16(kf1, qf1, st[mt], 0, 0, 0);
      }
      __builtin_amdgcn_s_setprio(0);
      // causal mask (only tiles that touch the diagonal for this wave)
      if (kt * 64 + 63 > q0 + 16 * w) {
#pragma unroll
        for (int mt = 0; mt < 4; ++mt)
#pragma unroll
          for (int r = 0; r < 4; ++r) {
            const int kr_g = kt * 64 + 16 * mt + rbase + r;
            if (kr_g > qrow) st[mt][r] = -__builtin_inff();
          }
      }
      // ---- online softmax, exp2 domain ----
      // tile max: balanced tree (max3-fusable)
      float mx[4];
#pragma unroll
      for (int mt = 0; mt < 4; ++mt)
        mx[mt] = fmaxf(fmaxf(st[mt][0], st[mt][1]), fmaxf(st[mt][2], st[mt][3]));
      float mloc = fmaxf(fmaxf(mx[0], mx[1]), fmaxf(mx[2], mx[3]));
      mloc = fmaxf(mloc, __shfl_xor(mloc, 16));
      mloc = fmaxf(mloc, __shfl_xor(mloc, 32));
      // defer-rescale: only pay the rescale when max grew by > 8 (2^8 bound)
      if (!__all(mloc - m_s <= 8.0f)) {
        const float mnew = fmaxf(m_s, mloc);
        const float corr = exp2f(m_s - mnew);   // first tile: exp2(-inf)=0
        l_p *= corr;
        float c4[4];
#pragma unroll
        for (int r = 0; r < 4; ++r) c4[r] = __shfl(corr, rbase + r);
#pragma unroll
        for (int nt = 0; nt < 4; ++nt)
#pragma unroll
          for (int r = 0; r < 4; ++r) o[nt][r] *= c4[r];
        m_s = mnew;
      }
      // p = exp2(s - m), tree partial sum (cross-lane reduce deferred)
#pragma unroll
      for (int mt = 0; mt < 4; ++mt)
#pragma unroll
        for (int r = 0; r < 4; ++r) st[mt][r] = exp2f(st[mt][r] - m_s);
      float s4[4];
#pragma unroll
      for (int mt = 0; mt < 4; ++mt)
        s4[mt] = (st[mt][0] + st[mt][1]) + (st[mt][2] + st[mt][3]);
      l_p += (s4[0] + s4[1]) + (s4[2] + s4[3]);

      // P -> per-wave LDS (cvt_pk bf16 pack, swizzled)
#pragma unroll
      for (int mt = 0; mt < 4; ++mt)
#pragma unroll
        for (int pr = 0; pr < 2; ++pr) {
          const int kr0 = 16 * mt + rbase + 2 * pr;
          uint32_t val;
          asm("v_cvt_pk_bf16_f32 %0, %1, %2"
              : "=v"(val) : "v"(st[mt][2 * pr]), "v"(st[mt][2 * pr + 1]));
          *(uint32_t*)((char*)Pw + llo * 128 + (((kr0 >> 3) ^ l7) << 4) +
                       (kr0 & 7) * 2) = val;
        }
      // PV
      __builtin_amdgcn_s_setprio(1);
#pragma unroll
      for (int ks = 0; ks < 2; ++ks) {
        const bf16x8 pf = *(const bf16x8*)(Pw + llo * 64 + (((lhi + 4 * ks) ^ l7) << 3));
#pragma unroll
        for (int nt = 0; nt < 4; ++nt) {
          const int d_l = 16 * nt + llo;
          const int fd = l7 ^ ((2 * nt + (llo >> 3)) & 7);
          const bf16x8 vf = *(const bf16x8*)(Vt[cur] + d_l * 64 +
                                             (((lhi + 4 * ks) ^ fd) << 3));
          o[nt] = __builtin_amdgcn_mfma_f32_16x16x32_bf16(pf, vf, o[nt], 0, 0, 0);
        }
      }
      __builtin_amdgcn_s_setprio(0);
    }

    // ---- write next V tile (regs -> LDS, after compute: T14 write-late) ----
    if (have_next) {
      const u16* p0 = (const u16*)&vr0;
      const u16* p1 = (const u16*)&vr1;
#pragma unroll
      for (int i = 0; i < 4; ++i) {
        const int d = vd4 + i;
        const uint32_t val = (uint32_t)p0[i] | ((uint32_t)p1[i] << 16);
        const int p = (vkr >> 3) ^ (d & 7) ^ ((d >> 3) & 7);
        *(uint32_t*)((char*)Vt[cur ^ 1] + d * 128 + (p << 4) + (vkr & 7) * 2) = val;
      }
    }
    __syncthreads();   // drains gload_lds (vmcnt) + orders Vt writes
    cur ^= 1;
  }

  // ---- epilogue: finish deferred l reduction, store bf16 ----
  float l_s = l_p;
  l_s += __shfl_xor(l_s, 16);
  l_s += __shfl_xor(l_s, 32);
  const float invl = 1.f / l_s;
  float i4[4];
#pragma unroll
  for (int r = 0; r < 4; ++r) i4[r] = __shfl(invl, rbase + r);
#pragma unroll
  for (int nt = 0; nt < 4; ++nt)
#pragma unroll
    for (int r = 0; r < 4; ++r) {
      const int qg = q0 + 16 * w + rbase + r;
      const int d = 16 * nt + llo;
      Yb[(size_t)(b * T_ + qg) * C_ + h * D_ + d] = f2bf(o[nt][r] * i4[r]);
    }
}

// ---------------------------------------------------------------------------
extern "C" void kernel_launch(void* const* d_in, const int* in_sizes, int n_in,
                              void* d_out, int out_size, void* d_ws, size_t ws_size,
                              hipStream_t stream) {
  (void)in_sizes; (void)n_in; (void)out_size; (void)ws_size;
  const float* x     = (const float*)d_in[0];
  const float* Wq    = (const float*)d_in[1];
  const float* Wkv   = (const float*)d_in[2];
  const float* Wproj = (const float*)d_in[3];
  const float* bproj = (const float*)d_in[4];
  float* out = (float*)d_out;

  const size_t M = (size_t)B_ * T_;   // 8192
  u16* xb    = (u16*)d_ws;            // [M,1024] bf16; later aliased as Yb
  u16* QKVb  = xb + M * C_;           // [M,1536] bf16 packed Q|K|V
  u16* wpb   = QKVb + M * QKV_;       // [1024,1024] bf16
  u16* wqkv  = (u16*)d_out;           // [1536,1024] bf16 scratch in out buffer
  u16* Yb    = xb;

  dim3 blk(256);
  cvt_bf16<<<2048, blk, 0, stream>>>(x, xb, (int)(M * C_ / 4), 1.f);
  // Wq scale = 1/8 (attn scale) * log2(e)  -> scores land in exp2 domain
  cvt_bf16<<<512, blk, 0, stream>>>(Wq, wqkv, C_ * C_ / 4, 0.125f * 1.44269504f);
  cvt_bf16<<<256, blk, 0, stream>>>(Wkv, wqkv + (size_t)C_ * C_, KVC_ * C_ / 4, 1.f);
  // fused QKV projection: [M,1024] @ [1536,1024]^T -> [M,1536]
  gemm_bf16<0><<<dim3(64, 12), blk, 0, stream>>>(xb, wqkv, nullptr, QKVb, QKV_, C_);
  // attention (writes Yb = xb; xb consumed by QKV GEMM above)
  attn_kernel<<<dim3(16, 64), dim3(512), 0, stream>>>(QKVb, Yb);
  // output projection + bias (f32 out; overwrites wqkv scratch region)
  cvt_bf16<<<512, blk, 0, stream>>>(Wproj, wpb, C_ * C_ / 4, 1.f);
  gemm_bf16<1><<<dim3(64, 8), blk, 0, stream>>>(Yb, wpb, bproj, out, C_, C_);
}